// Round 5
// baseline (4988.847 us; speedup 1.0000x reference)
//
#include <hip/hip_runtime.h>
#include <math.h>

#define HID 128
#define NB 32      // nodes per block in fused layer kernel
#define ECAP 2048  // edge records staged in LDS per block (16 KB)

typedef unsigned int uint32;
typedef unsigned short ushort_t;

__device__ __forceinline__ unsigned short f2bf(float f) {
    unsigned u = __float_as_uint(f);
    u += 0x7FFF + ((u >> 16) & 1);          // round-to-nearest-even
    return (unsigned short)(u >> 16);
}
__device__ __forceinline__ float bf_lo(uint32 u) { return __uint_as_float(u << 16); }
__device__ __forceinline__ float bf_hi(uint32 u) { return __uint_as_float(u & 0xFFFF0000u); }

// ---------- CSR build ----------
__global__ void degree_k(const int* __restrict__ col, int* __restrict__ counts, int E) {
    int e = blockIdx.x * 256 + threadIdx.x;
    if (e < E) atomicAdd(&counts[col[e]], 1);
}

__global__ void dinv_k(const int* __restrict__ counts, float* __restrict__ dinv, int N) {
    int i = blockIdx.x * 256 + threadIdx.x;
    if (i < N) dinv[i] = rsqrtf((float)counts[i] + 1.0f);
}

__global__ void scan1_k(const int* __restrict__ counts, int* __restrict__ row_ptr,
                        int* __restrict__ blocksums, int N) {
    __shared__ int tmp[256];
    int t = threadIdx.x;
    int i = blockIdx.x * 256 + t;
    int v = (i < N) ? counts[i] : 0;
    tmp[t] = v;
    __syncthreads();
    for (int off = 1; off < 256; off <<= 1) {
        int x = (t >= off) ? tmp[t - off] : 0;
        __syncthreads();
        tmp[t] += x;
        __syncthreads();
    }
    if (i < N) row_ptr[i] = tmp[t] - v;
    if (t == 255) blocksums[blockIdx.x] = tmp[t];
}

__global__ void scan2_k(const int* __restrict__ blocksums, int* __restrict__ blockoffs, int nb) {
    __shared__ int tmp[512];
    int t = threadIdx.x;
    int v = (t < nb) ? blocksums[t] : 0;
    tmp[t] = v;
    __syncthreads();
    for (int off = 1; off < 512; off <<= 1) {
        int x = (t >= off) ? tmp[t - off] : 0;
        __syncthreads();
        tmp[t] += x;
        __syncthreads();
    }
    if (t < nb) blockoffs[t] = tmp[t] - v;
}

__global__ void scan3_k(int* __restrict__ row_ptr, const int* __restrict__ blockoffs, int N, int E) {
    int i = blockIdx.x * 256 + threadIdx.x;
    if (i < N) row_ptr[i] += blockoffs[blockIdx.x];
    if (i == 0) row_ptr[N] = E;
}

// edges[pos] = {src_node, bitcast(norm)} — one 8B record per edge
__global__ void scatter_k(const int* __restrict__ row, const int* __restrict__ col,
                          const float* __restrict__ dinv, int* __restrict__ cursor,
                          int2* __restrict__ edges, int E) {
    int e = blockIdx.x * 256 + threadIdx.x;
    if (e < E) {
        int c = col[e], r = row[e];
        int pos = atomicAdd(&cursor[c], 1);
        edges[pos] = make_int2(r, __float_as_int(dinv[r] * dinv[c]));
    }
}

// ---------- h0 = relu(x @ W_in + b_in) (fp32), h = bf16(h0) ----------
__global__ __launch_bounds__(256) void h0_k(const float* __restrict__ x,
                                            const float* __restrict__ Win,
                                            const float* __restrict__ bin,
                                            float* __restrict__ h0,
                                            ushort_t* __restrict__ h,
                                            int N) {
    __shared__ float xs[NB * 256];   // 32 KB
    int t = threadIdx.x;
    int base = blockIdx.x * NB;
    const float4* x4 = (const float4*)(x + (size_t)base * 256);
    float4* xs4 = (float4*)xs;
    for (int idx = t; idx < 2048; idx += 256) xs4[idx] = x4[idx];
    __syncthreads();

    int jq = t & 31, mg = t >> 5;     // 4 nodes x 4 feats per thread
    float4 acc[4];
#pragma unroll
    for (int m = 0; m < 4; m++) acc[m] = make_float4(0.f, 0.f, 0.f, 0.f);
    const float4* W4 = (const float4*)Win;

    // depth-2 register pipeline on W loads
    float4 wb[2][4];
#pragma unroll
    for (int u = 0; u < 4; u++) wb[0][u] = W4[u * 32 + jq];
#pragma unroll
    for (int u = 0; u < 4; u++) wb[1][u] = W4[(4 + u) * 32 + jq];

    for (int k = 0; k < 256; k += 4) {
        int cur = (k >> 2) & 1;
        float4 w0 = wb[cur][0], w1 = wb[cur][1], w2 = wb[cur][2], w3 = wb[cur][3];
        if (k + 8 < 256) {
#pragma unroll
            for (int u = 0; u < 4; u++) wb[cur][u] = W4[(k + 8 + u) * 32 + jq];
        }
#pragma unroll
        for (int m = 0; m < 4; m++) {
            float4 a = *(const float4*)&xs[(mg * 4 + m) * 256 + k];  // ds_read_b128
            acc[m].x += a.x * w0.x; acc[m].y += a.x * w0.y; acc[m].z += a.x * w0.z; acc[m].w += a.x * w0.w;
            acc[m].x += a.y * w1.x; acc[m].y += a.y * w1.y; acc[m].z += a.y * w1.z; acc[m].w += a.y * w1.w;
            acc[m].x += a.z * w2.x; acc[m].y += a.z * w2.y; acc[m].z += a.z * w2.z; acc[m].w += a.z * w2.w;
            acc[m].x += a.w * w3.x; acc[m].y += a.w * w3.y; acc[m].z += a.w * w3.z; acc[m].w += a.w * w3.w;
        }
    }
    float4 b4 = ((const float4*)bin)[jq];
#pragma unroll
    for (int m = 0; m < 4; m++) {
        int n = base + mg * 4 + m;
        if (n < N) {
            float4 r;
            r.x = fmaxf(acc[m].x + b4.x, 0.f);
            r.y = fmaxf(acc[m].y + b4.y, 0.f);
            r.z = fmaxf(acc[m].z + b4.z, 0.f);
            r.w = fmaxf(acc[m].w + b4.w, 0.f);
            *(float4*)&h0[(size_t)n * HID + jq * 4] = r;
            ushort4 hb;
            hb.x = f2bf(r.x); hb.y = f2bf(r.y); hb.z = f2bf(r.z); hb.w = f2bf(r.w);
            *(ushort4*)&h[(size_t)n * HID + jq * 4] = hb;
        }
    }
}

// ---------- fused layer: s = 0.9*Ahat@h + 0.1*h0 ; h_out = relu((1-b)s + b*(s@W)) ----------
// Phase A: block's edge records (contiguous in CSR) staged into LDS; per-wave
// gather loop reads records from LDS (lgkm pipe) and keeps 8 gathers in flight.
__global__ __launch_bounds__(256) void layer_k(const ushort_t* __restrict__ h_in,
                                               ushort_t* __restrict__ h_out,
                                               const float* __restrict__ h0,
                                               const float* __restrict__ dinv,
                                               const int* __restrict__ row_ptr,
                                               const int2* __restrict__ edges,
                                               const float* __restrict__ W,
                                               float beta, int N) {
    __shared__ float s_lds[NB * HID];   // 16 KB
    __shared__ int2  eds[ECAP];         // 16 KB
    int t = threadIdx.x;
    int lane = t & 63;
    int wv = t >> 6;
    int base = blockIdx.x * NB;
    int nEnd = min(base + NB, N);

    int blkBeg = row_ptr[base];
    int tot = row_ptr[nEnd] - blkBeg;
    int stg = min(tot, ECAP);
    for (int i = t; i < stg; i += 256) eds[i] = edges[blkBeg + i];  // coalesced
    __syncthreads();

    for (int m = wv; m < NB; m += 4) {
        int dst = base + m;
        if (dst >= N) {
            s_lds[m * HID + lane * 2] = 0.f;
            s_lds[m * HID + lane * 2 + 1] = 0.f;
            continue;
        }
        float dv = dinv[dst];
        float dv2 = dv * dv;
        uint32 hu = ((const uint32*)(h_in + (size_t)dst * HID))[lane];
        float ax = bf_lo(hu) * dv2, ay = bf_hi(hu) * dv2;
        int beg = row_ptr[dst] - blkBeg;
        int end = row_ptr[dst + 1] - blkBeg;
        int eS = min(end, stg);
        int e = beg;
        for (; e + 8 <= eS; e += 8) {
            int2 q0 = eds[e + 0], q1 = eds[e + 1], q2 = eds[e + 2], q3 = eds[e + 3];
            int2 q4 = eds[e + 4], q5 = eds[e + 5], q6 = eds[e + 6], q7 = eds[e + 7];
            uint32 g0 = ((const uint32*)(h_in + (size_t)q0.x * HID))[lane];
            uint32 g1 = ((const uint32*)(h_in + (size_t)q1.x * HID))[lane];
            uint32 g2 = ((const uint32*)(h_in + (size_t)q2.x * HID))[lane];
            uint32 g3 = ((const uint32*)(h_in + (size_t)q3.x * HID))[lane];
            uint32 g4 = ((const uint32*)(h_in + (size_t)q4.x * HID))[lane];
            uint32 g5 = ((const uint32*)(h_in + (size_t)q5.x * HID))[lane];
            uint32 g6 = ((const uint32*)(h_in + (size_t)q6.x * HID))[lane];
            uint32 g7 = ((const uint32*)(h_in + (size_t)q7.x * HID))[lane];
            float w0 = __int_as_float(q0.y), w1 = __int_as_float(q1.y);
            float w2 = __int_as_float(q2.y), w3 = __int_as_float(q3.y);
            float w4 = __int_as_float(q4.y), w5 = __int_as_float(q5.y);
            float w6 = __int_as_float(q6.y), w7 = __int_as_float(q7.y);
            ax += bf_lo(g0) * w0; ay += bf_hi(g0) * w0;
            ax += bf_lo(g1) * w1; ay += bf_hi(g1) * w1;
            ax += bf_lo(g2) * w2; ay += bf_hi(g2) * w2;
            ax += bf_lo(g3) * w3; ay += bf_hi(g3) * w3;
            ax += bf_lo(g4) * w4; ay += bf_hi(g4) * w4;
            ax += bf_lo(g5) * w5; ay += bf_hi(g5) * w5;
            ax += bf_lo(g6) * w6; ay += bf_hi(g6) * w6;
            ax += bf_lo(g7) * w7; ay += bf_hi(g7) * w7;
        }
        for (; e < eS; e++) {
            int2 q = eds[e];
            uint32 g = ((const uint32*)(h_in + (size_t)q.x * HID))[lane];
            float w = __int_as_float(q.y);
            ax += bf_lo(g) * w; ay += bf_hi(g) * w;
        }
        for (; e < end; e++) {   // fallback: block had >ECAP edges (rare)
            int2 q = edges[blkBeg + e];
            uint32 g = ((const uint32*)(h_in + (size_t)q.x * HID))[lane];
            float w = __int_as_float(q.y);
            ax += bf_lo(g) * w; ay += bf_hi(g) * w;
        }
        float2 h0v = *(const float2*)&h0[(size_t)dst * HID + lane * 2];
        s_lds[m * HID + lane * 2]     = 0.9f * ax + 0.1f * h0v.x;
        s_lds[m * HID + lane * 2 + 1] = 0.9f * ay + 0.1f * h0v.y;
    }
    __syncthreads();

    // Phase B: y = s @ W (fp32, register-tiled, depth-2 W prefetch)
    int jq = t & 31, mg = t >> 5;
    float4 acc[4];
#pragma unroll
    for (int m = 0; m < 4; m++) acc[m] = make_float4(0.f, 0.f, 0.f, 0.f);
    const float4* W4 = (const float4*)W;
    float4 wb[2][4];
#pragma unroll
    for (int u = 0; u < 4; u++) wb[0][u] = W4[u * 32 + jq];
#pragma unroll
    for (int u = 0; u < 4; u++) wb[1][u] = W4[(4 + u) * 32 + jq];
    for (int k = 0; k < HID; k += 4) {
        int cur = (k >> 2) & 1;
        float4 w0 = wb[cur][0], w1 = wb[cur][1], w2 = wb[cur][2], w3 = wb[cur][3];
        if (k + 8 < HID) {
#pragma unroll
            for (int u = 0; u < 4; u++) wb[cur][u] = W4[(k + 8 + u) * 32 + jq];
        }
#pragma unroll
        for (int m = 0; m < 4; m++) {
            float4 a = *(const float4*)&s_lds[(mg * 4 + m) * HID + k];  // ds_read_b128
            acc[m].x += a.x * w0.x; acc[m].y += a.x * w0.y; acc[m].z += a.x * w0.z; acc[m].w += a.x * w0.w;
            acc[m].x += a.y * w1.x; acc[m].y += a.y * w1.y; acc[m].z += a.y * w1.z; acc[m].w += a.y * w1.w;
            acc[m].x += a.z * w2.x; acc[m].y += a.z * w2.y; acc[m].z += a.z * w2.z; acc[m].w += a.z * w2.w;
            acc[m].x += a.w * w3.x; acc[m].y += a.w * w3.y; acc[m].z += a.w * w3.z; acc[m].w += a.w * w3.w;
        }
    }
    float ob = 1.0f - beta;
#pragma unroll
    for (int m = 0; m < 4; m++) {
        int mm = mg * 4 + m;
        int dst = base + mm;
        if (dst < N) {
            float4 sv = *(const float4*)&s_lds[mm * HID + jq * 4];
            ushort4 hb;
            hb.x = f2bf(fmaxf(ob * sv.x + beta * acc[m].x, 0.f));
            hb.y = f2bf(fmaxf(ob * sv.y + beta * acc[m].y, 0.f));
            hb.z = f2bf(fmaxf(ob * sv.z + beta * acc[m].z, 0.f));
            hb.w = f2bf(fmaxf(ob * sv.w + beta * acc[m].w, 0.f));
            *(ushort4*)&h_out[(size_t)dst * HID + jq * 4] = hb;
        }
    }
}

// ---------- out = h @ W_out + b_out ----------
__global__ void out_k(const ushort_t* __restrict__ h, const float* __restrict__ Wout,
                      const float* __restrict__ bout, float* __restrict__ out, int N) {
    int t = threadIdx.x;
    int lane = t & 63;
    int wv = t >> 6;  // 4 waves/block, one node each
    int n = blockIdx.x * 4 + wv;
    if (n >= N) return;
    uint32 u = ((const uint32*)(h + (size_t)n * HID))[lane];
    float v = bf_lo(u) * Wout[lane * 2] + bf_hi(u) * Wout[lane * 2 + 1];
#pragma unroll
    for (int off = 32; off > 0; off >>= 1) v += __shfl_down(v, off, 64);
    if (lane == 0) out[n] = v + bout[0];
}

extern "C" void kernel_launch(void* const* d_in, const int* in_sizes, int n_in,
                              void* d_out, int out_size, void* d_ws, size_t ws_size,
                              hipStream_t stream) {
    const float* x    = (const float*)d_in[0];
    const int*   ei   = (const int*)d_in[1];
    const float* Win  = (const float*)d_in[2];
    const float* bin  = (const float*)d_in[3];
    const float* convs= (const float*)d_in[4];
    const float* Wout = (const float*)d_in[5];
    const float* bout = (const float*)d_in[6];

    int N = in_sizes[0] / 256;
    int E = in_sizes[1] / 2;
    const int* row = ei;       // sources
    const int* col = ei + E;   // destinations

    char* ws = (char*)d_ws;
    size_t off = 0;
    auto alloc = [&](size_t bytes) -> char* {
        char* p = ws + off;
        off = (off + bytes + 255) & ~(size_t)255;
        return p;
    };
    int*      counts    = (int*)alloc((size_t)N * 4);
    int*      row_ptr   = (int*)alloc((size_t)(N + 1) * 4);
    int*      cursor    = (int*)alloc((size_t)N * 4);
    int*      blocksums = (int*)alloc(512 * 4);
    int*      blockoffs = (int*)alloc(512 * 4);
    float*    dinv      = (float*)alloc((size_t)N * 4);
    int2*     edges     = (int2*)alloc((size_t)E * 8);
    float*    h0        = (float*)alloc((size_t)N * HID * 4);
    ushort_t* hA        = (ushort_t*)alloc((size_t)N * HID * 2);
    ushort_t* hB        = (ushort_t*)alloc((size_t)N * HID * 2);

    int eb = (E + 255) / 256;
    int nb = (N + 255) / 256;

    hipMemsetAsync(counts, 0, (size_t)N * 4, stream);
    degree_k<<<eb, 256, 0, stream>>>(col, counts, E);
    dinv_k<<<nb, 256, 0, stream>>>(counts, dinv, N);
    scan1_k<<<nb, 256, 0, stream>>>(counts, row_ptr, blocksums, N);
    scan2_k<<<1, 512, 0, stream>>>(blocksums, blockoffs, nb);
    scan3_k<<<nb, 256, 0, stream>>>(row_ptr, blockoffs, N, E);
    hipMemcpyAsync(cursor, row_ptr, (size_t)N * 4, hipMemcpyDeviceToDevice, stream);
    scatter_k<<<eb, 256, 0, stream>>>(row, col, dinv, cursor, edges, E);

    int gb = (N + NB - 1) / NB;
    h0_k<<<gb, 256, 0, stream>>>(x, Win, bin, h0, hA, N);

    ushort_t* hin = hA;
    ushort_t* hout = hB;
    for (int i = 0; i < 8; i++) {
        float beta = (float)log(0.5 / (double)(i + 1) + 1.0);
        layer_k<<<gb, 256, 0, stream>>>(hin, hout, h0, dinv, row_ptr, edges,
                                        convs + (size_t)i * HID * HID, beta, N);
        ushort_t* tp = hin; hin = hout; hout = tp;
    }
    out_k<<<(N + 3) / 4, 256, 0, stream>>>(hin, Wout, bout, (float*)d_out, N);
}

// Round 6
// 1595.275 us; speedup vs baseline: 3.1273x; 3.1273x over previous
//
#include <hip/hip_runtime.h>
#include <math.h>

#define HID 128
#define NB 32      // nodes per block in fused layer kernel
#define ECAP 2048  // edge records staged in LDS per block (16 KB)

typedef unsigned int uint32;
typedef unsigned short ushort_t;

__device__ __forceinline__ unsigned short f2bf(float f) {
    unsigned u = __float_as_uint(f);
    u += 0x7FFF + ((u >> 16) & 1);          // round-to-nearest-even
    return (unsigned short)(u >> 16);
}
__device__ __forceinline__ float bf_lo(uint32 u) { return __uint_as_float(u << 16); }
__device__ __forceinline__ float bf_hi(uint32 u) { return __uint_as_float(u & 0xFFFF0000u); }

// ---------- CSR build ----------
__global__ void degree_k(const int* __restrict__ col, int* __restrict__ counts, int E) {
    int e = blockIdx.x * 256 + threadIdx.x;
    if (e < E) atomicAdd(&counts[col[e]], 1);
}

__global__ void dinv_k(const int* __restrict__ counts, float* __restrict__ dinv, int N) {
    int i = blockIdx.x * 256 + threadIdx.x;
    if (i < N) dinv[i] = rsqrtf((float)counts[i] + 1.0f);
}

__global__ void scan1_k(const int* __restrict__ counts, int* __restrict__ row_ptr,
                        int* __restrict__ blocksums, int N) {
    __shared__ int tmp[256];
    int t = threadIdx.x;
    int i = blockIdx.x * 256 + t;
    int v = (i < N) ? counts[i] : 0;
    tmp[t] = v;
    __syncthreads();
    for (int off = 1; off < 256; off <<= 1) {
        int x = (t >= off) ? tmp[t - off] : 0;
        __syncthreads();
        tmp[t] += x;
        __syncthreads();
    }
    if (i < N) row_ptr[i] = tmp[t] - v;
    if (t == 255) blocksums[blockIdx.x] = tmp[t];
}

__global__ void scan2_k(const int* __restrict__ blocksums, int* __restrict__ blockoffs, int nb) {
    __shared__ int tmp[512];
    int t = threadIdx.x;
    int v = (t < nb) ? blocksums[t] : 0;
    tmp[t] = v;
    __syncthreads();
    for (int off = 1; off < 512; off <<= 1) {
        int x = (t >= off) ? tmp[t - off] : 0;
        __syncthreads();
        tmp[t] += x;
        __syncthreads();
    }
    if (t < nb) blockoffs[t] = tmp[t] - v;
}

__global__ void scan3_k(int* __restrict__ row_ptr, const int* __restrict__ blockoffs, int N, int E) {
    int i = blockIdx.x * 256 + threadIdx.x;
    if (i < N) row_ptr[i] += blockoffs[blockIdx.x];
    if (i == 0) row_ptr[N] = E;
}

// edges[pos] = {src_node, bitcast(norm)} — one 8B record per edge
__global__ void scatter_k(const int* __restrict__ row, const int* __restrict__ col,
                          const float* __restrict__ dinv, int* __restrict__ cursor,
                          int2* __restrict__ edges, int E) {
    int e = blockIdx.x * 256 + threadIdx.x;
    if (e < E) {
        int c = col[e], r = row[e];
        int pos = atomicAdd(&cursor[c], 1);
        edges[pos] = make_int2(r, __float_as_int(dinv[r] * dinv[c]));
    }
}

// ---------- h0 = relu(x @ W_in + b_in) (fp32), h = bf16(h0) ----------
__global__ __launch_bounds__(256) void h0_k(const float* __restrict__ x,
                                            const float* __restrict__ Win,
                                            const float* __restrict__ bin,
                                            float* __restrict__ h0,
                                            ushort_t* __restrict__ h,
                                            int N) {
    __shared__ float xs[NB * 256];   // 32 KB
    int t = threadIdx.x;
    int base = blockIdx.x * NB;
    const float4* x4 = (const float4*)(x + (size_t)base * 256);
    float4* xs4 = (float4*)xs;
    for (int idx = t; idx < 2048; idx += 256) xs4[idx] = x4[idx];
    __syncthreads();

    int jq = t & 31, mg = t >> 5;     // 4 nodes x 4 feats per thread
    float4 acc[4];
#pragma unroll
    for (int m = 0; m < 4; m++) acc[m] = make_float4(0.f, 0.f, 0.f, 0.f);
    const float4* W4 = (const float4*)Win;
    for (int k = 0; k < 256; k += 4) {
        float4 w0 = W4[(k + 0) * 32 + jq];
        float4 w1 = W4[(k + 1) * 32 + jq];
        float4 w2 = W4[(k + 2) * 32 + jq];
        float4 w3 = W4[(k + 3) * 32 + jq];
#pragma unroll
        for (int m = 0; m < 4; m++) {
            float4 a = *(const float4*)&xs[(mg * 4 + m) * 256 + k];  // ds_read_b128
            acc[m].x += a.x * w0.x; acc[m].y += a.x * w0.y; acc[m].z += a.x * w0.z; acc[m].w += a.x * w0.w;
            acc[m].x += a.y * w1.x; acc[m].y += a.y * w1.y; acc[m].z += a.y * w1.z; acc[m].w += a.y * w1.w;
            acc[m].x += a.z * w2.x; acc[m].y += a.z * w2.y; acc[m].z += a.z * w2.z; acc[m].w += a.z * w2.w;
            acc[m].x += a.w * w3.x; acc[m].y += a.w * w3.y; acc[m].z += a.w * w3.z; acc[m].w += a.w * w3.w;
        }
    }
    float4 b4 = ((const float4*)bin)[jq];
#pragma unroll
    for (int m = 0; m < 4; m++) {
        int n = base + mg * 4 + m;
        if (n < N) {
            float4 r;
            r.x = fmaxf(acc[m].x + b4.x, 0.f);
            r.y = fmaxf(acc[m].y + b4.y, 0.f);
            r.z = fmaxf(acc[m].z + b4.z, 0.f);
            r.w = fmaxf(acc[m].w + b4.w, 0.f);
            *(float4*)&h0[(size_t)n * HID + jq * 4] = r;
            ushort4 hb;
            hb.x = f2bf(r.x); hb.y = f2bf(r.y); hb.z = f2bf(r.z); hb.w = f2bf(r.w);
            *(ushort4*)&h[(size_t)n * HID + jq * 4] = hb;
        }
    }
}

// ---------- fused layer: s = 0.9*Ahat@h + 0.1*h0 ; h_out = relu((1-b)s + b*(s@W)) ----------
// Phase A: block's edge records (contiguous in CSR) staged into LDS; per-wave
// gather loop reads records from LDS (lgkm pipe) and keeps 8 gathers in flight.
__global__ __launch_bounds__(256) void layer_k(const ushort_t* __restrict__ h_in,
                                               ushort_t* __restrict__ h_out,
                                               const float* __restrict__ h0,
                                               const float* __restrict__ dinv,
                                               const int* __restrict__ row_ptr,
                                               const int2* __restrict__ edges,
                                               const float* __restrict__ W,
                                               float beta, int N) {
    __shared__ float s_lds[NB * HID];   // 16 KB
    __shared__ int2  eds[ECAP];         // 16 KB
    int t = threadIdx.x;
    int lane = t & 63;
    int wv = t >> 6;
    int base = blockIdx.x * NB;
    int nEnd = min(base + NB, N);

    int blkBeg = row_ptr[base];
    int tot = row_ptr[nEnd] - blkBeg;
    int stg = min(tot, ECAP);
    for (int i = t; i < stg; i += 256) eds[i] = edges[blkBeg + i];  // coalesced
    __syncthreads();

    for (int m = wv; m < NB; m += 4) {
        int dst = base + m;
        if (dst >= N) {
            s_lds[m * HID + lane * 2] = 0.f;
            s_lds[m * HID + lane * 2 + 1] = 0.f;
            continue;
        }
        float dv = dinv[dst];
        float dv2 = dv * dv;
        uint32 hu = ((const uint32*)(h_in + (size_t)dst * HID))[lane];
        float ax = bf_lo(hu) * dv2, ay = bf_hi(hu) * dv2;
        int beg = row_ptr[dst] - blkBeg;
        int end = row_ptr[dst + 1] - blkBeg;
        int eS = min(end, stg);
        int e = beg;
        for (; e + 8 <= eS; e += 8) {
            int2 q0 = eds[e + 0], q1 = eds[e + 1], q2 = eds[e + 2], q3 = eds[e + 3];
            int2 q4 = eds[e + 4], q5 = eds[e + 5], q6 = eds[e + 6], q7 = eds[e + 7];
            uint32 g0 = ((const uint32*)(h_in + (size_t)q0.x * HID))[lane];
            uint32 g1 = ((const uint32*)(h_in + (size_t)q1.x * HID))[lane];
            uint32 g2 = ((const uint32*)(h_in + (size_t)q2.x * HID))[lane];
            uint32 g3 = ((const uint32*)(h_in + (size_t)q3.x * HID))[lane];
            uint32 g4 = ((const uint32*)(h_in + (size_t)q4.x * HID))[lane];
            uint32 g5 = ((const uint32*)(h_in + (size_t)q5.x * HID))[lane];
            uint32 g6 = ((const uint32*)(h_in + (size_t)q6.x * HID))[lane];
            uint32 g7 = ((const uint32*)(h_in + (size_t)q7.x * HID))[lane];
            float w0 = __int_as_float(q0.y), w1 = __int_as_float(q1.y);
            float w2 = __int_as_float(q2.y), w3 = __int_as_float(q3.y);
            float w4 = __int_as_float(q4.y), w5 = __int_as_float(q5.y);
            float w6 = __int_as_float(q6.y), w7 = __int_as_float(q7.y);
            ax += bf_lo(g0) * w0; ay += bf_hi(g0) * w0;
            ax += bf_lo(g1) * w1; ay += bf_hi(g1) * w1;
            ax += bf_lo(g2) * w2; ay += bf_hi(g2) * w2;
            ax += bf_lo(g3) * w3; ay += bf_hi(g3) * w3;
            ax += bf_lo(g4) * w4; ay += bf_hi(g4) * w4;
            ax += bf_lo(g5) * w5; ay += bf_hi(g5) * w5;
            ax += bf_lo(g6) * w6; ay += bf_hi(g6) * w6;
            ax += bf_lo(g7) * w7; ay += bf_hi(g7) * w7;
        }
        for (; e < eS; e++) {
            int2 q = eds[e];
            uint32 g = ((const uint32*)(h_in + (size_t)q.x * HID))[lane];
            float w = __int_as_float(q.y);
            ax += bf_lo(g) * w; ay += bf_hi(g) * w;
        }
        for (; e < end; e++) {   // fallback: block had >ECAP edges (rare)
            int2 q = edges[blkBeg + e];
            uint32 g = ((const uint32*)(h_in + (size_t)q.x * HID))[lane];
            float w = __int_as_float(q.y);
            ax += bf_lo(g) * w; ay += bf_hi(g) * w;
        }
        float2 h0v = *(const float2*)&h0[(size_t)dst * HID + lane * 2];
        s_lds[m * HID + lane * 2]     = 0.9f * ax + 0.1f * h0v.x;
        s_lds[m * HID + lane * 2 + 1] = 0.9f * ay + 0.1f * h0v.y;
    }
    __syncthreads();

    // Phase B: y = s @ W (fp32, register-tiled: 4 nodes x 4 feats per thread)
    int jq = t & 31, mg = t >> 5;
    float4 acc[4];
#pragma unroll
    for (int m = 0; m < 4; m++) acc[m] = make_float4(0.f, 0.f, 0.f, 0.f);
    const float4* W4 = (const float4*)W;
    for (int k = 0; k < HID; k += 4) {
        float4 w0 = W4[(k + 0) * 32 + jq];
        float4 w1 = W4[(k + 1) * 32 + jq];
        float4 w2 = W4[(k + 2) * 32 + jq];
        float4 w3 = W4[(k + 3) * 32 + jq];
#pragma unroll
        for (int m = 0; m < 4; m++) {
            float4 a = *(const float4*)&s_lds[(mg * 4 + m) * HID + k];  // ds_read_b128
            acc[m].x += a.x * w0.x; acc[m].y += a.x * w0.y; acc[m].z += a.x * w0.z; acc[m].w += a.x * w0.w;
            acc[m].x += a.y * w1.x; acc[m].y += a.y * w1.y; acc[m].z += a.y * w1.z; acc[m].w += a.y * w1.w;
            acc[m].x += a.z * w2.x; acc[m].y += a.z * w2.y; acc[m].z += a.z * w2.z; acc[m].w += a.z * w2.w;
            acc[m].x += a.w * w3.x; acc[m].y += a.w * w3.y; acc[m].z += a.w * w3.z; acc[m].w += a.w * w3.w;
        }
    }
    float ob = 1.0f - beta;
#pragma unroll
    for (int m = 0; m < 4; m++) {
        int mm = mg * 4 + m;
        int dst = base + mm;
        if (dst < N) {
            float4 sv = *(const float4*)&s_lds[mm * HID + jq * 4];
            ushort4 hb;
            hb.x = f2bf(fmaxf(ob * sv.x + beta * acc[m].x, 0.f));
            hb.y = f2bf(fmaxf(ob * sv.y + beta * acc[m].y, 0.f));
            hb.z = f2bf(fmaxf(ob * sv.z + beta * acc[m].z, 0.f));
            hb.w = f2bf(fmaxf(ob * sv.w + beta * acc[m].w, 0.f));
            *(ushort4*)&h_out[(size_t)dst * HID + jq * 4] = hb;
        }
    }
}

// ---------- out = h @ W_out + b_out ----------
__global__ void out_k(const ushort_t* __restrict__ h, const float* __restrict__ Wout,
                      const float* __restrict__ bout, float* __restrict__ out, int N) {
    int t = threadIdx.x;
    int lane = t & 63;
    int wv = t >> 6;  // 4 waves/block, one node each
    int n = blockIdx.x * 4 + wv;
    if (n >= N) return;
    uint32 u = ((const uint32*)(h + (size_t)n * HID))[lane];
    float v = bf_lo(u) * Wout[lane * 2] + bf_hi(u) * Wout[lane * 2 + 1];
#pragma unroll
    for (int off = 32; off > 0; off >>= 1) v += __shfl_down(v, off, 64);
    if (lane == 0) out[n] = v + bout[0];
}

extern "C" void kernel_launch(void* const* d_in, const int* in_sizes, int n_in,
                              void* d_out, int out_size, void* d_ws, size_t ws_size,
                              hipStream_t stream) {
    const float* x    = (const float*)d_in[0];
    const int*   ei   = (const int*)d_in[1];
    const float* Win  = (const float*)d_in[2];
    const float* bin  = (const float*)d_in[3];
    const float* convs= (const float*)d_in[4];
    const float* Wout = (const float*)d_in[5];
    const float* bout = (const float*)d_in[6];

    int N = in_sizes[0] / 256;
    int E = in_sizes[1] / 2;
    const int* row = ei;       // sources
    const int* col = ei + E;   // destinations

    char* ws = (char*)d_ws;
    size_t off = 0;
    auto alloc = [&](size_t bytes) -> char* {
        char* p = ws + off;
        off = (off + bytes + 255) & ~(size_t)255;
        return p;
    };
    int*      counts    = (int*)alloc((size_t)N * 4);
    int*      row_ptr   = (int*)alloc((size_t)(N + 1) * 4);
    int*      cursor    = (int*)alloc((size_t)N * 4);
    int*      blocksums = (int*)alloc(512 * 4);
    int*      blockoffs = (int*)alloc(512 * 4);
    float*    dinv      = (float*)alloc((size_t)N * 4);
    int2*     edges     = (int2*)alloc((size_t)E * 8);
    float*    h0        = (float*)alloc((size_t)N * HID * 4);
    ushort_t* hA        = (ushort_t*)alloc((size_t)N * HID * 2);
    ushort_t* hB        = (ushort_t*)alloc((size_t)N * HID * 2);

    int eb = (E + 255) / 256;
    int nb = (N + 255) / 256;

    hipMemsetAsync(counts, 0, (size_t)N * 4, stream);
    degree_k<<<eb, 256, 0, stream>>>(col, counts, E);
    dinv_k<<<nb, 256, 0, stream>>>(counts, dinv, N);
    scan1_k<<<nb, 256, 0, stream>>>(counts, row_ptr, blocksums, N);
    scan2_k<<<1, 512, 0, stream>>>(blocksums, blockoffs, nb);
    scan3_k<<<nb, 256, 0, stream>>>(row_ptr, blockoffs, N, E);
    hipMemcpyAsync(cursor, row_ptr, (size_t)N * 4, hipMemcpyDeviceToDevice, stream);
    scatter_k<<<eb, 256, 0, stream>>>(row, col, dinv, cursor, edges, E);

    int gb = (N + NB - 1) / NB;
    h0_k<<<gb, 256, 0, stream>>>(x, Win, bin, h0, hA, N);

    ushort_t* hin = hA;
    ushort_t* hout = hB;
    for (int i = 0; i < 8; i++) {
        float beta = (float)log(0.5 / (double)(i + 1) + 1.0);
        layer_k<<<gb, 256, 0, stream>>>(hin, hout, h0, dinv, row_ptr, edges,
                                        convs + (size_t)i * HID * HID, beta, N);
        ushort_t* tp = hin; hin = hout; hout = tp;
    }
    out_k<<<(N + 3) / 4, 256, 0, stream>>>(hin, Wout, bout, (float*)d_out, N);
}

// Round 7
// 1331.551 us; speedup vs baseline: 3.7466x; 1.1981x over previous
//
#include <hip/hip_runtime.h>
#include <math.h>

#define HID 128
#define NB 32   // nodes per block in fused layer kernel

typedef unsigned int uint32;
typedef unsigned short ushort_t;

__device__ __forceinline__ unsigned short f2bf(float f) {
    unsigned u = __float_as_uint(f);
    u += 0x7FFF + ((u >> 16) & 1);          // round-to-nearest-even
    return (unsigned short)(u >> 16);
}
__device__ __forceinline__ float bf_lo(uint32 u) { return __uint_as_float(u << 16); }
__device__ __forceinline__ float bf_hi(uint32 u) { return __uint_as_float(u & 0xFFFF0000u); }

// ---------- CSR build ----------
__global__ void degree_k(const int* __restrict__ col, int* __restrict__ counts, int E) {
    int e = blockIdx.x * 256 + threadIdx.x;
    if (e < E) atomicAdd(&counts[col[e]], 1);
}

__global__ void dinv_k(const int* __restrict__ counts, float* __restrict__ dinv, int N) {
    int i = blockIdx.x * 256 + threadIdx.x;
    if (i < N) dinv[i] = rsqrtf((float)counts[i] + 1.0f);
}

__global__ void scan1_k(const int* __restrict__ counts, int* __restrict__ row_ptr,
                        int* __restrict__ blocksums, int N) {
    __shared__ int tmp[256];
    int t = threadIdx.x;
    int i = blockIdx.x * 256 + t;
    int v = (i < N) ? counts[i] : 0;
    tmp[t] = v;
    __syncthreads();
    for (int off = 1; off < 256; off <<= 1) {
        int x = (t >= off) ? tmp[t - off] : 0;
        __syncthreads();
        tmp[t] += x;
        __syncthreads();
    }
    if (i < N) row_ptr[i] = tmp[t] - v;
    if (t == 255) blocksums[blockIdx.x] = tmp[t];
}

__global__ void scan2_k(const int* __restrict__ blocksums, int* __restrict__ blockoffs, int nb) {
    __shared__ int tmp[512];
    int t = threadIdx.x;
    int v = (t < nb) ? blocksums[t] : 0;
    tmp[t] = v;
    __syncthreads();
    for (int off = 1; off < 512; off <<= 1) {
        int x = (t >= off) ? tmp[t - off] : 0;
        __syncthreads();
        tmp[t] += x;
        __syncthreads();
    }
    if (t < nb) blockoffs[t] = tmp[t] - v;
}

__global__ void scan3_k(int* __restrict__ row_ptr, const int* __restrict__ blockoffs, int N, int E) {
    int i = blockIdx.x * 256 + threadIdx.x;
    if (i < N) row_ptr[i] += blockoffs[blockIdx.x];
    if (i == 0) row_ptr[N] = E;
}

// srcS[pos] = source node — 4 B/edge; norms are folded into g = dinv*h
__global__ void scatter_k(const int* __restrict__ row, const int* __restrict__ col,
                          int* __restrict__ cursor, int* __restrict__ srcS, int E) {
    int e = blockIdx.x * 256 + threadIdx.x;
    if (e < E) {
        int pos = atomicAdd(&cursor[col[e]], 1);
        srcS[pos] = row[e];
    }
}

// ---------- h0 = relu(x @ W_in + b_in); writes h0b = bf16(h0), g = bf16(dinv*h0) ----------
__global__ __launch_bounds__(256) void h0_k(const float* __restrict__ x,
                                            const float* __restrict__ Win,
                                            const float* __restrict__ bin,
                                            const float* __restrict__ dinv,
                                            ushort_t* __restrict__ h0b,
                                            ushort_t* __restrict__ g,
                                            int N) {
    __shared__ float xs[NB * 256];   // 32 KB
    int t = threadIdx.x;
    int base = blockIdx.x * NB;
    const float4* x4 = (const float4*)(x + (size_t)base * 256);
    float4* xs4 = (float4*)xs;
    for (int idx = t; idx < 2048; idx += 256) xs4[idx] = x4[idx];
    __syncthreads();

    int jq = t & 31, mg = t >> 5;     // 4 nodes x 4 feats per thread
    float4 acc[4];
#pragma unroll
    for (int m = 0; m < 4; m++) acc[m] = make_float4(0.f, 0.f, 0.f, 0.f);
    const float4* W4 = (const float4*)Win;
    for (int k = 0; k < 256; k += 4) {
        float4 w0 = W4[(k + 0) * 32 + jq];
        float4 w1 = W4[(k + 1) * 32 + jq];
        float4 w2 = W4[(k + 2) * 32 + jq];
        float4 w3 = W4[(k + 3) * 32 + jq];
#pragma unroll
        for (int m = 0; m < 4; m++) {
            float4 a = *(const float4*)&xs[(mg * 4 + m) * 256 + k];  // ds_read_b128
            acc[m].x += a.x * w0.x; acc[m].y += a.x * w0.y; acc[m].z += a.x * w0.z; acc[m].w += a.x * w0.w;
            acc[m].x += a.y * w1.x; acc[m].y += a.y * w1.y; acc[m].z += a.y * w1.z; acc[m].w += a.y * w1.w;
            acc[m].x += a.z * w2.x; acc[m].y += a.z * w2.y; acc[m].z += a.z * w2.z; acc[m].w += a.z * w2.w;
            acc[m].x += a.w * w3.x; acc[m].y += a.w * w3.y; acc[m].z += a.w * w3.z; acc[m].w += a.w * w3.w;
        }
    }
    float4 b4 = ((const float4*)bin)[jq];
#pragma unroll
    for (int m = 0; m < 4; m++) {
        int n = base + mg * 4 + m;
        if (n < N) {
            float dv = dinv[n];
            float rx = fmaxf(acc[m].x + b4.x, 0.f);
            float ry = fmaxf(acc[m].y + b4.y, 0.f);
            float rz = fmaxf(acc[m].z + b4.z, 0.f);
            float rw = fmaxf(acc[m].w + b4.w, 0.f);
            ushort4 hb, gb;
            hb.x = f2bf(rx); hb.y = f2bf(ry); hb.z = f2bf(rz); hb.w = f2bf(rw);
            gb.x = f2bf(dv * rx); gb.y = f2bf(dv * ry); gb.z = f2bf(dv * rz); gb.w = f2bf(dv * rw);
            *(ushort4*)&h0b[(size_t)n * HID + jq * 4] = hb;
            *(ushort4*)&g[(size_t)n * HID + jq * 4] = gb;
        }
    }
}

// ---------- fused layer (g-space): T = g[dst] + sum_nbr g[src];
// s = 0.9*dinv[dst]*T + 0.1*h0 ; h_next = relu((1-b)s + b*(s@W)); g_out = bf16(dinv*h_next)
__global__ __launch_bounds__(256) void layer_k(const ushort_t* __restrict__ g_in,
                                               ushort_t* __restrict__ g_out,
                                               const ushort_t* __restrict__ h0b,
                                               const float* __restrict__ dinv,
                                               const int* __restrict__ row_ptr,
                                               const int* __restrict__ srcS,
                                               const float* __restrict__ W,
                                               float beta, int N) {
    __shared__ float s_lds[NB * HID];   // 16 KB
    int t = threadIdx.x;
    int lane = t & 63;
    int wv = t >> 6;
    int base = blockIdx.x * NB;

    for (int m = wv; m < NB; m += 4) {
        int dst = base + m;
        if (dst >= N) {
            s_lds[m * HID + lane * 2] = 0.f;
            s_lds[m * HID + lane * 2 + 1] = 0.f;
            continue;
        }
        float dv = dinv[dst];
        uint32 gd = ((const uint32*)(g_in + (size_t)dst * HID))[lane];
        float ax = bf_lo(gd), ay = bf_hi(gd);   // self term: +g[dst]
        int beg = __builtin_amdgcn_readfirstlane(row_ptr[dst]);
        int end = __builtin_amdgcn_readfirstlane(row_ptr[dst + 1]);
        int e = beg;
        for (; e + 8 <= end; e += 8) {          // 8 independent gathers in flight
            int s0 = __builtin_amdgcn_readfirstlane(srcS[e + 0]);
            int s1 = __builtin_amdgcn_readfirstlane(srcS[e + 1]);
            int s2 = __builtin_amdgcn_readfirstlane(srcS[e + 2]);
            int s3 = __builtin_amdgcn_readfirstlane(srcS[e + 3]);
            int s4 = __builtin_amdgcn_readfirstlane(srcS[e + 4]);
            int s5 = __builtin_amdgcn_readfirstlane(srcS[e + 5]);
            int s6 = __builtin_amdgcn_readfirstlane(srcS[e + 6]);
            int s7 = __builtin_amdgcn_readfirstlane(srcS[e + 7]);
            uint32 g0 = ((const uint32*)(g_in + (size_t)s0 * HID))[lane];
            uint32 g1 = ((const uint32*)(g_in + (size_t)s1 * HID))[lane];
            uint32 g2 = ((const uint32*)(g_in + (size_t)s2 * HID))[lane];
            uint32 g3 = ((const uint32*)(g_in + (size_t)s3 * HID))[lane];
            uint32 g4 = ((const uint32*)(g_in + (size_t)s4 * HID))[lane];
            uint32 g5 = ((const uint32*)(g_in + (size_t)s5 * HID))[lane];
            uint32 g6 = ((const uint32*)(g_in + (size_t)s6 * HID))[lane];
            uint32 g7 = ((const uint32*)(g_in + (size_t)s7 * HID))[lane];
            ax += bf_lo(g0); ay += bf_hi(g0);
            ax += bf_lo(g1); ay += bf_hi(g1);
            ax += bf_lo(g2); ay += bf_hi(g2);
            ax += bf_lo(g3); ay += bf_hi(g3);
            ax += bf_lo(g4); ay += bf_hi(g4);
            ax += bf_lo(g5); ay += bf_hi(g5);
            ax += bf_lo(g6); ay += bf_hi(g6);
            ax += bf_lo(g7); ay += bf_hi(g7);
        }
        for (; e < end; e++) {
            int sn = __builtin_amdgcn_readfirstlane(srcS[e]);
            uint32 gg = ((const uint32*)(g_in + (size_t)sn * HID))[lane];
            ax += bf_lo(gg); ay += bf_hi(gg);
        }
        uint32 hu = ((const uint32*)(h0b + (size_t)dst * HID))[lane];
        float sc = 0.9f * dv;
        s_lds[m * HID + lane * 2]     = sc * ax + 0.1f * bf_lo(hu);
        s_lds[m * HID + lane * 2 + 1] = sc * ay + 0.1f * bf_hi(hu);
    }
    __syncthreads();

    // Phase B: y = s @ W (fp32, register-tiled: 4 nodes x 4 feats per thread)
    int jq = t & 31, mg = t >> 5;
    float4 acc[4];
#pragma unroll
    for (int m = 0; m < 4; m++) acc[m] = make_float4(0.f, 0.f, 0.f, 0.f);
    const float4* W4 = (const float4*)W;
    for (int k = 0; k < HID; k += 4) {
        float4 w0 = W4[(k + 0) * 32 + jq];
        float4 w1 = W4[(k + 1) * 32 + jq];
        float4 w2 = W4[(k + 2) * 32 + jq];
        float4 w3 = W4[(k + 3) * 32 + jq];
#pragma unroll
        for (int m = 0; m < 4; m++) {
            float4 a = *(const float4*)&s_lds[(mg * 4 + m) * HID + k];  // ds_read_b128
            acc[m].x += a.x * w0.x; acc[m].y += a.x * w0.y; acc[m].z += a.x * w0.z; acc[m].w += a.x * w0.w;
            acc[m].x += a.y * w1.x; acc[m].y += a.y * w1.y; acc[m].z += a.y * w1.z; acc[m].w += a.y * w1.w;
            acc[m].x += a.z * w2.x; acc[m].y += a.z * w2.y; acc[m].z += a.z * w2.z; acc[m].w += a.z * w2.w;
            acc[m].x += a.w * w3.x; acc[m].y += a.w * w3.y; acc[m].z += a.w * w3.z; acc[m].w += a.w * w3.w;
        }
    }
    float ob = 1.0f - beta;
#pragma unroll
    for (int m = 0; m < 4; m++) {
        int mm = mg * 4 + m;
        int dst = base + mm;
        if (dst < N) {
            float dvm = dinv[dst];
            float4 sv = *(const float4*)&s_lds[mm * HID + jq * 4];
            float hx = fmaxf(ob * sv.x + beta * acc[m].x, 0.f);
            float hy = fmaxf(ob * sv.y + beta * acc[m].y, 0.f);
            float hz = fmaxf(ob * sv.z + beta * acc[m].z, 0.f);
            float hw = fmaxf(ob * sv.w + beta * acc[m].w, 0.f);
            ushort4 gb;
            gb.x = f2bf(dvm * hx); gb.y = f2bf(dvm * hy);
            gb.z = f2bf(dvm * hz); gb.w = f2bf(dvm * hw);
            *(ushort4*)&g_out[(size_t)dst * HID + jq * 4] = gb;
        }
    }
}

// ---------- out = (g/dinv) @ W_out + b_out ----------
__global__ void out_k(const ushort_t* __restrict__ g, const float* __restrict__ dinv,
                      const float* __restrict__ Wout, const float* __restrict__ bout,
                      float* __restrict__ out, int N) {
    int t = threadIdx.x;
    int lane = t & 63;
    int wv = t >> 6;  // 4 waves/block, one node each
    int n = blockIdx.x * 4 + wv;
    if (n >= N) return;
    uint32 u = ((const uint32*)(g + (size_t)n * HID))[lane];
    float v = bf_lo(u) * Wout[lane * 2] + bf_hi(u) * Wout[lane * 2 + 1];
#pragma unroll
    for (int off = 32; off > 0; off >>= 1) v += __shfl_down(v, off, 64);
    if (lane == 0) out[n] = v / dinv[n] + bout[0];
}

extern "C" void kernel_launch(void* const* d_in, const int* in_sizes, int n_in,
                              void* d_out, int out_size, void* d_ws, size_t ws_size,
                              hipStream_t stream) {
    const float* x    = (const float*)d_in[0];
    const int*   ei   = (const int*)d_in[1];
    const float* Win  = (const float*)d_in[2];
    const float* bin  = (const float*)d_in[3];
    const float* convs= (const float*)d_in[4];
    const float* Wout = (const float*)d_in[5];
    const float* bout = (const float*)d_in[6];

    int N = in_sizes[0] / 256;
    int E = in_sizes[1] / 2;
    const int* row = ei;       // sources
    const int* col = ei + E;   // destinations

    char* ws = (char*)d_ws;
    size_t off = 0;
    auto alloc = [&](size_t bytes) -> char* {
        char* p = ws + off;
        off = (off + bytes + 255) & ~(size_t)255;
        return p;
    };
    int*      counts    = (int*)alloc((size_t)N * 4);
    int*      row_ptr   = (int*)alloc((size_t)(N + 1) * 4);
    int*      cursor    = (int*)alloc((size_t)N * 4);
    int*      blocksums = (int*)alloc(512 * 4);
    int*      blockoffs = (int*)alloc(512 * 4);
    float*    dinv      = (float*)alloc((size_t)N * 4);
    int*      srcS      = (int*)alloc((size_t)E * 4);
    ushort_t* h0b       = (ushort_t*)alloc((size_t)N * HID * 2);
    ushort_t* gA        = (ushort_t*)alloc((size_t)N * HID * 2);
    ushort_t* gB        = (ushort_t*)alloc((size_t)N * HID * 2);

    int eb = (E + 255) / 256;
    int nb = (N + 255) / 256;

    hipMemsetAsync(counts, 0, (size_t)N * 4, stream);
    degree_k<<<eb, 256, 0, stream>>>(col, counts, E);
    dinv_k<<<nb, 256, 0, stream>>>(counts, dinv, N);
    scan1_k<<<nb, 256, 0, stream>>>(counts, row_ptr, blocksums, N);
    scan2_k<<<1, 512, 0, stream>>>(blocksums, blockoffs, nb);
    scan3_k<<<nb, 256, 0, stream>>>(row_ptr, blockoffs, N, E);
    hipMemcpyAsync(cursor, row_ptr, (size_t)N * 4, hipMemcpyDeviceToDevice, stream);
    scatter_k<<<eb, 256, 0, stream>>>(row, col, cursor, srcS, E);

    int gb = (N + NB - 1) / NB;
    h0_k<<<gb, 256, 0, stream>>>(x, Win, bin, dinv, h0b, gA, N);

    ushort_t* gin = gA;
    ushort_t* gout = gB;
    for (int i = 0; i < 8; i++) {
        float beta = (float)log(0.5 / (double)(i + 1) + 1.0);
        layer_k<<<gb, 256, 0, stream>>>(gin, gout, h0b, dinv, row_ptr, srcS,
                                        convs + (size_t)i * HID * HID, beta, N);
        ushort_t* tp = gin; gin = gout; gout = tp;
    }
    out_k<<<(N + 3) / 4, 256, 0, stream>>>(gin, dinv, Wout, bout, (float*)d_out, N);
}

// Round 8
// 1294.460 us; speedup vs baseline: 3.8540x; 1.0287x over previous
//
#include <hip/hip_runtime.h>
#include <math.h>

#define HID 128
#define NB 32     // nodes per block in fused layer kernel
#define SBST 136  // padded bf16 row stride for s_bf (16B-aligned, low bank conflict)

typedef unsigned int uint32;
typedef unsigned short ushort_t;
typedef __attribute__((ext_vector_type(8))) short bf16x8;
typedef __attribute__((ext_vector_type(4))) float f32x4;

__device__ __forceinline__ unsigned short f2bf(float f) {
    unsigned u = __float_as_uint(f);
    u += 0x7FFF + ((u >> 16) & 1);          // round-to-nearest-even
    return (unsigned short)(u >> 16);
}
__device__ __forceinline__ float bf_lo(uint32 u) { return __uint_as_float(u << 16); }
__device__ __forceinline__ float bf_hi(uint32 u) { return __uint_as_float(u & 0xFFFF0000u); }

// ---------- CSR build ----------
__global__ void degree_k(const int* __restrict__ col, int* __restrict__ counts, int E) {
    int e = blockIdx.x * 256 + threadIdx.x;
    if (e < E) atomicAdd(&counts[col[e]], 1);
}

__global__ void dinv_k(const int* __restrict__ counts, float* __restrict__ dinv, int N) {
    int i = blockIdx.x * 256 + threadIdx.x;
    if (i < N) dinv[i] = rsqrtf((float)counts[i] + 1.0f);
}

__global__ void scan1_k(const int* __restrict__ counts, int* __restrict__ row_ptr,
                        int* __restrict__ blocksums, int N) {
    __shared__ int tmp[256];
    int t = threadIdx.x;
    int i = blockIdx.x * 256 + t;
    int v = (i < N) ? counts[i] : 0;
    tmp[t] = v;
    __syncthreads();
    for (int off = 1; off < 256; off <<= 1) {
        int x = (t >= off) ? tmp[t - off] : 0;
        __syncthreads();
        tmp[t] += x;
        __syncthreads();
    }
    if (i < N) row_ptr[i] = tmp[t] - v;
    if (t == 255) blocksums[blockIdx.x] = tmp[t];
}

__global__ void scan2_k(const int* __restrict__ blocksums, int* __restrict__ blockoffs, int nb) {
    __shared__ int tmp[512];
    int t = threadIdx.x;
    int v = (t < nb) ? blocksums[t] : 0;
    tmp[t] = v;
    __syncthreads();
    for (int off = 1; off < 512; off <<= 1) {
        int x = (t >= off) ? tmp[t - off] : 0;
        __syncthreads();
        tmp[t] += x;
        __syncthreads();
    }
    if (t < nb) blockoffs[t] = tmp[t] - v;
}

__global__ void scan3_k(int* __restrict__ row_ptr, const int* __restrict__ blockoffs, int N, int E) {
    int i = blockIdx.x * 256 + threadIdx.x;
    if (i < N) row_ptr[i] += blockoffs[blockIdx.x];
    if (i == 0) row_ptr[N] = E;
}

// srcS[pos] = source node — 4 B/edge; norms folded into g = dinv*h
__global__ void scatter_k(const int* __restrict__ row, const int* __restrict__ col,
                          int* __restrict__ cursor, int* __restrict__ srcS, int E) {
    int e = blockIdx.x * 256 + threadIdx.x;
    if (e < E) {
        int pos = atomicAdd(&cursor[col[e]], 1);
        srcS[pos] = row[e];
    }
}

// ---------- Wt[l][n][k] = bf16(convs[l][k][n]) : B^T bf16 layout for MFMA ----------
__global__ void wprep_k(const float* __restrict__ convs, short* __restrict__ Wt) {
    int idx = blockIdx.x * 256 + threadIdx.x;
    if (idx >= 8 * 128 * 128) return;
    int l = idx >> 14;
    int r = idx & 16383;
    int k = r >> 7;
    int n = r & 127;                     // n fastest -> coalesced read
    Wt[(l << 14) + (n << 7) + k] = (short)f2bf(convs[idx]);
}

// ---------- h0 = relu(x @ W_in + b_in); writes h0b = bf16(h0), g = bf16(dinv*h0) ----------
__global__ __launch_bounds__(256) void h0_k(const float* __restrict__ x,
                                            const float* __restrict__ Win,
                                            const float* __restrict__ bin,
                                            const float* __restrict__ dinv,
                                            ushort_t* __restrict__ h0b,
                                            ushort_t* __restrict__ g,
                                            int N) {
    __shared__ float xs[NB * 256];   // 32 KB
    int t = threadIdx.x;
    int base = blockIdx.x * NB;
    const float4* x4 = (const float4*)(x + (size_t)base * 256);
    float4* xs4 = (float4*)xs;
    for (int idx = t; idx < 2048; idx += 256) xs4[idx] = x4[idx];
    __syncthreads();

    int jq = t & 31, mg = t >> 5;     // 4 nodes x 4 feats per thread
    float4 acc[4];
#pragma unroll
    for (int m = 0; m < 4; m++) acc[m] = make_float4(0.f, 0.f, 0.f, 0.f);
    const float4* W4 = (const float4*)Win;
    for (int k = 0; k < 256; k += 4) {
        float4 w0 = W4[(k + 0) * 32 + jq];
        float4 w1 = W4[(k + 1) * 32 + jq];
        float4 w2 = W4[(k + 2) * 32 + jq];
        float4 w3 = W4[(k + 3) * 32 + jq];
#pragma unroll
        for (int m = 0; m < 4; m++) {
            float4 a = *(const float4*)&xs[(mg * 4 + m) * 256 + k];  // ds_read_b128
            acc[m].x += a.x * w0.x; acc[m].y += a.x * w0.y; acc[m].z += a.x * w0.z; acc[m].w += a.x * w0.w;
            acc[m].x += a.y * w1.x; acc[m].y += a.y * w1.y; acc[m].z += a.y * w1.z; acc[m].w += a.y * w1.w;
            acc[m].x += a.z * w2.x; acc[m].y += a.z * w2.y; acc[m].z += a.z * w2.z; acc[m].w += a.z * w2.w;
            acc[m].x += a.w * w3.x; acc[m].y += a.w * w3.y; acc[m].z += a.w * w3.z; acc[m].w += a.w * w3.w;
        }
    }
    float4 b4 = ((const float4*)bin)[jq];
#pragma unroll
    for (int m = 0; m < 4; m++) {
        int n = base + mg * 4 + m;
        if (n < N) {
            float dv = dinv[n];
            float rx = fmaxf(acc[m].x + b4.x, 0.f);
            float ry = fmaxf(acc[m].y + b4.y, 0.f);
            float rz = fmaxf(acc[m].z + b4.z, 0.f);
            float rw = fmaxf(acc[m].w + b4.w, 0.f);
            ushort4 hb, gb;
            hb.x = f2bf(rx); hb.y = f2bf(ry); hb.z = f2bf(rz); hb.w = f2bf(rw);
            gb.x = f2bf(dv * rx); gb.y = f2bf(dv * ry); gb.z = f2bf(dv * rz); gb.w = f2bf(dv * rw);
            *(ushort4*)&h0b[(size_t)n * HID + jq * 4] = hb;
            *(ushort4*)&g[(size_t)n * HID + jq * 4] = gb;
        }
    }
}

// ---------- fused layer (g-space): T = g[dst] + sum_nbr g[src];
// s = 0.9*dinv[dst]*T + 0.1*h0 ; h_next = relu((1-b)s + b*(s@W)) via MFMA;
// g_out = bf16(dinv*h_next)
__global__ __launch_bounds__(256) void layer_k(const ushort_t* __restrict__ g_in,
                                               ushort_t* __restrict__ g_out,
                                               const ushort_t* __restrict__ h0b,
                                               const float* __restrict__ dinv,
                                               const int* __restrict__ row_ptr,
                                               const int* __restrict__ srcS,
                                               const short* __restrict__ Wtb,
                                               float beta, int N) {
    __shared__ float s_f32[NB * HID];   // 16 KB — fp32 s for epilogue
    __shared__ short s_bf[NB * SBST];   // 8.5 KB — bf16 s for MFMA A-frags
    __shared__ float s_dv[NB];
    int t = threadIdx.x;
    int lane = t & 63;
    int wv = t >> 6;
    int base = blockIdx.x * NB;

    if (t < NB) s_dv[t] = dinv[base + t];

    // ---- Phase A: gather-aggregate (wave per node, 8 gathers in flight) ----
    for (int m = wv; m < NB; m += 4) {
        int dst = base + m;
        if (dst >= N) {
            s_f32[m * HID + lane * 2] = 0.f;
            s_f32[m * HID + lane * 2 + 1] = 0.f;
            *(uint32*)&s_bf[m * SBST + lane * 2] = 0;
            continue;
        }
        float dv = dinv[dst];
        uint32 gd = ((const uint32*)(g_in + (size_t)dst * HID))[lane];
        float ax = bf_lo(gd), ay = bf_hi(gd);   // self term: +g[dst]
        int beg = __builtin_amdgcn_readfirstlane(row_ptr[dst]);
        int end = __builtin_amdgcn_readfirstlane(row_ptr[dst + 1]);
        int e = beg;
        for (; e + 8 <= end; e += 8) {
            int s0 = __builtin_amdgcn_readfirstlane(srcS[e + 0]);
            int s1 = __builtin_amdgcn_readfirstlane(srcS[e + 1]);
            int s2 = __builtin_amdgcn_readfirstlane(srcS[e + 2]);
            int s3 = __builtin_amdgcn_readfirstlane(srcS[e + 3]);
            int s4 = __builtin_amdgcn_readfirstlane(srcS[e + 4]);
            int s5 = __builtin_amdgcn_readfirstlane(srcS[e + 5]);
            int s6 = __builtin_amdgcn_readfirstlane(srcS[e + 6]);
            int s7 = __builtin_amdgcn_readfirstlane(srcS[e + 7]);
            uint32 g0 = ((const uint32*)(g_in + (size_t)s0 * HID))[lane];
            uint32 g1 = ((const uint32*)(g_in + (size_t)s1 * HID))[lane];
            uint32 g2 = ((const uint32*)(g_in + (size_t)s2 * HID))[lane];
            uint32 g3 = ((const uint32*)(g_in + (size_t)s3 * HID))[lane];
            uint32 g4 = ((const uint32*)(g_in + (size_t)s4 * HID))[lane];
            uint32 g5 = ((const uint32*)(g_in + (size_t)s5 * HID))[lane];
            uint32 g6 = ((const uint32*)(g_in + (size_t)s6 * HID))[lane];
            uint32 g7 = ((const uint32*)(g_in + (size_t)s7 * HID))[lane];
            ax += bf_lo(g0); ay += bf_hi(g0);
            ax += bf_lo(g1); ay += bf_hi(g1);
            ax += bf_lo(g2); ay += bf_hi(g2);
            ax += bf_lo(g3); ay += bf_hi(g3);
            ax += bf_lo(g4); ay += bf_hi(g4);
            ax += bf_lo(g5); ay += bf_hi(g5);
            ax += bf_lo(g6); ay += bf_hi(g6);
            ax += bf_lo(g7); ay += bf_hi(g7);
        }
        for (; e < end; e++) {
            int sn = __builtin_amdgcn_readfirstlane(srcS[e]);
            uint32 gg = ((const uint32*)(g_in + (size_t)sn * HID))[lane];
            ax += bf_lo(gg); ay += bf_hi(gg);
        }
        uint32 hu = ((const uint32*)(h0b + (size_t)dst * HID))[lane];
        float sc = 0.9f * dv;
        float sx = sc * ax + 0.1f * bf_lo(hu);
        float sy = sc * ay + 0.1f * bf_hi(hu);
        s_f32[m * HID + lane * 2]     = sx;
        s_f32[m * HID + lane * 2 + 1] = sy;
        uint32 pk = ((uint32)f2bf(sy) << 16) | (uint32)f2bf(sx);
        *(uint32*)&s_bf[m * SBST + lane * 2] = pk;
    }
    __syncthreads();

    // ---- Phase B: y = s @ W via MFMA 16x16x32 bf16 ----
    // wave wv: m-tile = (wv&1)*16 ; j-tiles = ((wv>>1) + 2q)*16, q=0..3
    int mt = (wv & 1) * 16;
    int jb = wv >> 1;
    int lrow = lane & 15;
    int lq = lane >> 4;
    f32x4 acc0 = {0.f, 0.f, 0.f, 0.f};
    f32x4 acc1 = {0.f, 0.f, 0.f, 0.f};
    f32x4 acc2 = {0.f, 0.f, 0.f, 0.f};
    f32x4 acc3 = {0.f, 0.f, 0.f, 0.f};
#pragma unroll
    for (int ks = 0; ks < 4; ks++) {
        bf16x8 a = *(const bf16x8*)&s_bf[(mt + lrow) * SBST + ks * 32 + lq * 8];
        bf16x8 b0 = *(const bf16x8*)&Wtb[((jb + 0) * 16 + lrow) * 128 + ks * 32 + lq * 8];
        bf16x8 b1 = *(const bf16x8*)&Wtb[((jb + 2) * 16 + lrow) * 128 + ks * 32 + lq * 8];
        bf16x8 b2 = *(const bf16x8*)&Wtb[((jb + 4) * 16 + lrow) * 128 + ks * 32 + lq * 8];
        bf16x8 b3 = *(const bf16x8*)&Wtb[((jb + 6) * 16 + lrow) * 128 + ks * 32 + lq * 8];
        acc0 = __builtin_amdgcn_mfma_f32_16x16x32_bf16(a, b0, acc0, 0, 0, 0);
        acc1 = __builtin_amdgcn_mfma_f32_16x16x32_bf16(a, b1, acc1, 0, 0, 0);
        acc2 = __builtin_amdgcn_mfma_f32_16x16x32_bf16(a, b2, acc2, 0, 0, 0);
        acc3 = __builtin_amdgcn_mfma_f32_16x16x32_bf16(a, b3, acc3, 0, 0, 0);
    }

    float ob = 1.0f - beta;
#pragma unroll
    for (int q = 0; q < 4; q++) {
        f32x4 accq = (q == 0) ? acc0 : (q == 1) ? acc1 : (q == 2) ? acc2 : acc3;
        int j0 = (jb + 2 * q) * 16;
#pragma unroll
        for (int r = 0; r < 4; r++) {
            int rowm = mt + lq * 4 + r;          // C/D: col=lane&15, row=quad*4+reg
            int dst = base + rowm;
            if (dst < N) {
                float sv = s_f32[rowm * HID + j0 + lrow];
                float h = fmaxf(ob * sv + beta * accq[r], 0.f);
                g_out[(size_t)dst * HID + j0 + lrow] = f2bf(s_dv[rowm] * h);
            }
        }
    }
}

// ---------- out = (g/dinv) @ W_out + b_out ----------
__global__ void out_k(const ushort_t* __restrict__ g, const float* __restrict__ dinv,
                      const float* __restrict__ Wout, const float* __restrict__ bout,
                      float* __restrict__ out, int N) {
    int t = threadIdx.x;
    int lane = t & 63;
    int wv = t >> 6;  // 4 waves/block, one node each
    int n = blockIdx.x * 4 + wv;
    if (n >= N) return;
    uint32 u = ((const uint32*)(g + (size_t)n * HID))[lane];
    float v = bf_lo(u) * Wout[lane * 2] + bf_hi(u) * Wout[lane * 2 + 1];
#pragma unroll
    for (int off = 32; off > 0; off >>= 1) v += __shfl_down(v, off, 64);
    if (lane == 0) out[n] = v / dinv[n] + bout[0];
}

extern "C" void kernel_launch(void* const* d_in, const int* in_sizes, int n_in,
                              void* d_out, int out_size, void* d_ws, size_t ws_size,
                              hipStream_t stream) {
    const float* x    = (const float*)d_in[0];
    const int*   ei   = (const int*)d_in[1];
    const float* Win  = (const float*)d_in[2];
    const float* bin  = (const float*)d_in[3];
    const float* convs= (const float*)d_in[4];
    const float* Wout = (const float*)d_in[5];
    const float* bout = (const float*)d_in[6];

    int N = in_sizes[0] / 256;
    int E = in_sizes[1] / 2;
    const int* row = ei;       // sources
    const int* col = ei + E;   // destinations

    char* ws = (char*)d_ws;
    size_t off = 0;
    auto alloc = [&](size_t bytes) -> char* {
        char* p = ws + off;
        off = (off + bytes + 255) & ~(size_t)255;
        return p;
    };
    int*      counts    = (int*)alloc((size_t)N * 4);
    int*      row_ptr   = (int*)alloc((size_t)(N + 1) * 4);
    int*      cursor    = (int*)alloc((size_t)N * 4);
    int*      blocksums = (int*)alloc(512 * 4);
    int*      blockoffs = (int*)alloc(512 * 4);
    float*    dinv      = (float*)alloc((size_t)N * 4);
    int*      srcS      = (int*)alloc((size_t)E * 4);
    short*    Wt        = (short*)alloc((size_t)8 * 128 * 128 * 2);
    ushort_t* h0b       = (ushort_t*)alloc((size_t)N * HID * 2);
    ushort_t* gA        = (ushort_t*)alloc((size_t)N * HID * 2);
    ushort_t* gB        = (ushort_t*)alloc((size_t)N * HID * 2);

    int eb = (E + 255) / 256;
    int nb = (N + 255) / 256;

    hipMemsetAsync(counts, 0, (size_t)N * 4, stream);
    degree_k<<<eb, 256, 0, stream>>>(col, counts, E);
    dinv_k<<<nb, 256, 0, stream>>>(counts, dinv, N);
    scan1_k<<<nb, 256, 0, stream>>>(counts, row_ptr, blocksums, N);
    scan2_k<<<1, 512, 0, stream>>>(blocksums, blockoffs, nb);
    scan3_k<<<nb, 256, 0, stream>>>(row_ptr, blockoffs, N, E);
    hipMemcpyAsync(cursor, row_ptr, (size_t)N * 4, hipMemcpyDeviceToDevice, stream);
    scatter_k<<<eb, 256, 0, stream>>>(row, col, cursor, srcS, E);
    wprep_k<<<512, 256, 0, stream>>>(convs, Wt);

    int gb = (N + NB - 1) / NB;
    h0_k<<<gb, 256, 0, stream>>>(x, Win, bin, dinv, h0b, gA, N);

    ushort_t* gin = gA;
    ushort_t* gout = gB;
    for (int i = 0; i < 8; i++) {
        float beta = (float)log(0.5 / (double)(i + 1) + 1.0);
        layer_k<<<gb, 256, 0, stream>>>(gin, gout, h0b, dinv, row_ptr, srcS,
                                        Wt + (size_t)i * 128 * 128, beta, N);
        ushort_t* tp = gin; gin = gout; gout = tp;
    }
    out_k<<<(N + 3) / 4, 256, 0, stream>>>(gin, dinv, Wout, bout, (float*)d_out, N);
}

// Round 9
// 1254.335 us; speedup vs baseline: 3.9773x; 1.0320x over previous
//
#include <hip/hip_runtime.h>
#include <math.h>

#define HID 128
#define NB 32     // nodes per block
#define SBST 136  // padded bf16 row stride for s_bf (16B-aligned, 2-way banks)
#define XST 264   // padded bf16 row stride for x-tile (16B-aligned, 2-way banks)

typedef unsigned int uint32;
typedef unsigned short ushort_t;
typedef __attribute__((ext_vector_type(8))) short bf16x8;
typedef __attribute__((ext_vector_type(4))) float f32x4;

__device__ __forceinline__ unsigned short f2bf(float f) {
    unsigned u = __float_as_uint(f);
    u += 0x7FFF + ((u >> 16) & 1);          // round-to-nearest-even
    return (unsigned short)(u >> 16);
}
__device__ __forceinline__ float bf_lo(uint32 u) { return __uint_as_float(u << 16); }
__device__ __forceinline__ float bf_hi(uint32 u) { return __uint_as_float(u & 0xFFFF0000u); }

// ---------- CSR build ----------
__global__ void degree_k(const int* __restrict__ col, int* __restrict__ counts, int E) {
    int e = blockIdx.x * 256 + threadIdx.x;
    if (e < E) atomicAdd(&counts[col[e]], 1);
}

// scan1 also emits dinv = rsqrt(deg+1)
__global__ void scan1_k(const int* __restrict__ counts, int* __restrict__ row_ptr,
                        int* __restrict__ blocksums, float* __restrict__ dinv, int N) {
    __shared__ int tmp[256];
    int t = threadIdx.x;
    int i = blockIdx.x * 256 + t;
    int v = (i < N) ? counts[i] : 0;
    if (i < N) dinv[i] = rsqrtf((float)v + 1.0f);
    tmp[t] = v;
    __syncthreads();
    for (int off = 1; off < 256; off <<= 1) {
        int x = (t >= off) ? tmp[t - off] : 0;
        __syncthreads();
        tmp[t] += x;
        __syncthreads();
    }
    if (i < N) row_ptr[i] = tmp[t] - v;
    if (t == 255) blocksums[blockIdx.x] = tmp[t];
}

__global__ void scan2_k(const int* __restrict__ blocksums, int* __restrict__ blockoffs, int nb) {
    __shared__ int tmp[512];
    int t = threadIdx.x;
    int v = (t < nb) ? blocksums[t] : 0;
    tmp[t] = v;
    __syncthreads();
    for (int off = 1; off < 512; off <<= 1) {
        int x = (t >= off) ? tmp[t - off] : 0;
        __syncthreads();
        tmp[t] += x;
        __syncthreads();
    }
    if (t < nb) blockoffs[t] = tmp[t] - v;
}

// scan3 also initializes cursor (saves a d2d copy)
__global__ void scan3_k(int* __restrict__ row_ptr, int* __restrict__ cursor,
                        const int* __restrict__ blockoffs, int N, int E) {
    int i = blockIdx.x * 256 + threadIdx.x;
    if (i < N) {
        int v = row_ptr[i] + blockoffs[blockIdx.x];
        row_ptr[i] = v;
        cursor[i] = v;
    }
    if (i == 0) row_ptr[N] = E;
}

// srcS[pos] = source node — 4 B/edge; norms folded into g = dinv*h
__global__ void scatter_k(const int* __restrict__ row, const int* __restrict__ col,
                          int* __restrict__ cursor, int* __restrict__ srcS, int E) {
    int e = blockIdx.x * 256 + threadIdx.x;
    if (e < E) {
        int pos = atomicAdd(&cursor[col[e]], 1);
        srcS[pos] = row[e];
    }
}

// ---------- Wt[l][n][k] = bf16(convs[l][k][n]) : B^T bf16 layout for MFMA ----------
__global__ void wprep_k(const float* __restrict__ convs, short* __restrict__ Wt) {
    int idx = blockIdx.x * 256 + threadIdx.x;
    if (idx >= 8 * 128 * 128) return;
    int l = idx >> 14;
    int r = idx & 16383;
    int k = r >> 7;
    int n = r & 127;                     // n fastest -> coalesced read
    Wt[(l << 14) + (n << 7) + k] = (short)f2bf(convs[idx]);
}

// Winb[n][k] = bf16(Win[k][n]), n in [0,128), k in [0,256)
__global__ void winprep_k(const float* __restrict__ Win, short* __restrict__ Winb) {
    int idx = blockIdx.x * 256 + threadIdx.x;
    if (idx >= 256 * 128) return;
    int k = idx >> 7;
    int n = idx & 127;
    Winb[n * 256 + k] = (short)f2bf(Win[idx]);
}

// ---------- h0 via MFMA: h0 = relu(x @ W_in + b_in); h0b = bf16(h0), g = bf16(dinv*h0) ----------
__global__ __launch_bounds__(256) void h0_k(const float* __restrict__ x,
                                            const short* __restrict__ Winb,
                                            const float* __restrict__ bin,
                                            const float* __restrict__ dinv,
                                            ushort_t* __restrict__ h0b,
                                            ushort_t* __restrict__ g,
                                            int N) {
    __shared__ short xs[NB * XST];   // ~16.9 KB bf16 x-tile
    int t = threadIdx.x;
    int base = blockIdx.x * NB;

    // stage + fp32->bf16 convert: 32 nodes x 256 feats, float2 per thread-iter
    for (int idx = t; idx < NB * 128; idx += 256) {
        int m = idx >> 7;
        int kk = (idx & 127) * 2;
        int nn = base + m;
        float2 v = make_float2(0.f, 0.f);
        if (nn < N) v = *(const float2*)&x[(size_t)nn * 256 + kk];
        uint32 pk = ((uint32)f2bf(v.y) << 16) | (uint32)f2bf(v.x);
        *(uint32*)&xs[m * XST + kk] = pk;
    }
    __syncthreads();

    int lane = t & 63, wv = t >> 6;
    int mt = (wv & 1) * 16;
    int jb = wv >> 1;
    int lrow = lane & 15;
    int lq = lane >> 4;
    f32x4 acc0 = {0.f, 0.f, 0.f, 0.f};
    f32x4 acc1 = {0.f, 0.f, 0.f, 0.f};
    f32x4 acc2 = {0.f, 0.f, 0.f, 0.f};
    f32x4 acc3 = {0.f, 0.f, 0.f, 0.f};
#pragma unroll
    for (int ks = 0; ks < 8; ks++) {
        bf16x8 a = *(const bf16x8*)&xs[(mt + lrow) * XST + ks * 32 + lq * 8];
        bf16x8 b0 = *(const bf16x8*)&Winb[((jb + 0) * 16 + lrow) * 256 + ks * 32 + lq * 8];
        bf16x8 b1 = *(const bf16x8*)&Winb[((jb + 2) * 16 + lrow) * 256 + ks * 32 + lq * 8];
        bf16x8 b2 = *(const bf16x8*)&Winb[((jb + 4) * 16 + lrow) * 256 + ks * 32 + lq * 8];
        bf16x8 b3 = *(const bf16x8*)&Winb[((jb + 6) * 16 + lrow) * 256 + ks * 32 + lq * 8];
        acc0 = __builtin_amdgcn_mfma_f32_16x16x32_bf16(a, b0, acc0, 0, 0, 0);
        acc1 = __builtin_amdgcn_mfma_f32_16x16x32_bf16(a, b1, acc1, 0, 0, 0);
        acc2 = __builtin_amdgcn_mfma_f32_16x16x32_bf16(a, b2, acc2, 0, 0, 0);
        acc3 = __builtin_amdgcn_mfma_f32_16x16x32_bf16(a, b3, acc3, 0, 0, 0);
    }
#pragma unroll
    for (int q = 0; q < 4; q++) {
        f32x4 accq = (q == 0) ? acc0 : (q == 1) ? acc1 : (q == 2) ? acc2 : acc3;
        int j0 = (jb + 2 * q) * 16;
        float bj = bin[j0 + lrow];
#pragma unroll
        for (int r = 0; r < 4; r++) {
            int rowm = mt + lq * 4 + r;          // C/D: col=lane&15, row=quad*4+reg
            int dst = base + rowm;
            if (dst < N) {
                float h = fmaxf(accq[r] + bj, 0.f);
                h0b[(size_t)dst * HID + j0 + lrow] = f2bf(h);
                g[(size_t)dst * HID + j0 + lrow] = f2bf(dinv[dst] * h);
            }
        }
    }
}

// ---------- fused layer (g-space): T = g[dst] + sum_nbr g[src];
// s = 0.9*dinv[dst]*T + 0.1*h0 ; h_next = relu((1-b)s + b*(s@W)) via MFMA;
// g_out = bf16(dinv*h_next)
__global__ __launch_bounds__(256) void layer_k(const ushort_t* __restrict__ g_in,
                                               ushort_t* __restrict__ g_out,
                                               const ushort_t* __restrict__ h0b,
                                               const float* __restrict__ dinv,
                                               const int* __restrict__ row_ptr,
                                               const int* __restrict__ srcS,
                                               const short* __restrict__ Wtb,
                                               float beta, int N) {
    __shared__ float s_f32[NB * HID];   // 16 KB — fp32 s for epilogue
    __shared__ short s_bf[NB * SBST];   // 8.5 KB — bf16 s for MFMA A-frags
    __shared__ float s_dv[NB];
    int t = threadIdx.x;
    int lane = t & 63;
    int wv = t >> 6;
    int base = blockIdx.x * NB;

    if (t < NB) s_dv[t] = dinv[base + t];

    // ---- Phase A: gather-aggregate (wave per node, 8 gathers in flight) ----
    for (int m = wv; m < NB; m += 4) {
        int dst = base + m;
        if (dst >= N) {
            s_f32[m * HID + lane * 2] = 0.f;
            s_f32[m * HID + lane * 2 + 1] = 0.f;
            *(uint32*)&s_bf[m * SBST + lane * 2] = 0;
            continue;
        }
        float dv = dinv[dst];
        uint32 gd = ((const uint32*)(g_in + (size_t)dst * HID))[lane];
        float ax = bf_lo(gd), ay = bf_hi(gd);   // self term: +g[dst]
        int beg = __builtin_amdgcn_readfirstlane(row_ptr[dst]);
        int end = __builtin_amdgcn_readfirstlane(row_ptr[dst + 1]);
        int e = beg;
        for (; e + 8 <= end; e += 8) {
            int s0 = __builtin_amdgcn_readfirstlane(srcS[e + 0]);
            int s1 = __builtin_amdgcn_readfirstlane(srcS[e + 1]);
            int s2 = __builtin_amdgcn_readfirstlane(srcS[e + 2]);
            int s3 = __builtin_amdgcn_readfirstlane(srcS[e + 3]);
            int s4 = __builtin_amdgcn_readfirstlane(srcS[e + 4]);
            int s5 = __builtin_amdgcn_readfirstlane(srcS[e + 5]);
            int s6 = __builtin_amdgcn_readfirstlane(srcS[e + 6]);
            int s7 = __builtin_amdgcn_readfirstlane(srcS[e + 7]);
            uint32 g0 = ((const uint32*)(g_in + (size_t)s0 * HID))[lane];
            uint32 g1 = ((const uint32*)(g_in + (size_t)s1 * HID))[lane];
            uint32 g2 = ((const uint32*)(g_in + (size_t)s2 * HID))[lane];
            uint32 g3 = ((const uint32*)(g_in + (size_t)s3 * HID))[lane];
            uint32 g4 = ((const uint32*)(g_in + (size_t)s4 * HID))[lane];
            uint32 g5 = ((const uint32*)(g_in + (size_t)s5 * HID))[lane];
            uint32 g6 = ((const uint32*)(g_in + (size_t)s6 * HID))[lane];
            uint32 g7 = ((const uint32*)(g_in + (size_t)s7 * HID))[lane];
            ax += bf_lo(g0); ay += bf_hi(g0);
            ax += bf_lo(g1); ay += bf_hi(g1);
            ax += bf_lo(g2); ay += bf_hi(g2);
            ax += bf_lo(g3); ay += bf_hi(g3);
            ax += bf_lo(g4); ay += bf_hi(g4);
            ax += bf_lo(g5); ay += bf_hi(g5);
            ax += bf_lo(g6); ay += bf_hi(g6);
            ax += bf_lo(g7); ay += bf_hi(g7);
        }
        for (; e < end; e++) {
            int sn = __builtin_amdgcn_readfirstlane(srcS[e]);
            uint32 gg = ((const uint32*)(g_in + (size_t)sn * HID))[lane];
            ax += bf_lo(gg); ay += bf_hi(gg);
        }
        uint32 hu = ((const uint32*)(h0b + (size_t)dst * HID))[lane];
        float sc = 0.9f * dv;
        float sx = sc * ax + 0.1f * bf_lo(hu);
        float sy = sc * ay + 0.1f * bf_hi(hu);
        s_f32[m * HID + lane * 2]     = sx;
        s_f32[m * HID + lane * 2 + 1] = sy;
        uint32 pk = ((uint32)f2bf(sy) << 16) | (uint32)f2bf(sx);
        *(uint32*)&s_bf[m * SBST + lane * 2] = pk;
    }
    __syncthreads();

    // ---- Phase B: y = s @ W via MFMA 16x16x32 bf16 ----
    int mt = (wv & 1) * 16;
    int jb = wv >> 1;
    int lrow = lane & 15;
    int lq = lane >> 4;
    f32x4 acc0 = {0.f, 0.f, 0.f, 0.f};
    f32x4 acc1 = {0.f, 0.f, 0.f, 0.f};
    f32x4 acc2 = {0.f, 0.f, 0.f, 0.f};
    f32x4 acc3 = {0.f, 0.f, 0.f, 0.f};
#pragma unroll
    for (int ks = 0; ks < 4; ks++) {
        bf16x8 a = *(const bf16x8*)&s_bf[(mt + lrow) * SBST + ks * 32 + lq * 8];
        bf16x8 b0 = *(const bf16x8*)&Wtb[((jb + 0) * 16 + lrow) * 128 + ks * 32 + lq * 8];
        bf16x8 b1 = *(const bf16x8*)&Wtb[((jb + 2) * 16 + lrow) * 128 + ks * 32 + lq * 8];
        bf16x8 b2 = *(const bf16x8*)&Wtb[((jb + 4) * 16 + lrow) * 128 + ks * 32 + lq * 8];
        bf16x8 b3 = *(const bf16x8*)&Wtb[((jb + 6) * 16 + lrow) * 128 + ks * 32 + lq * 8];
        acc0 = __builtin_amdgcn_mfma_f32_16x16x32_bf16(a, b0, acc0, 0, 0, 0);
        acc1 = __builtin_amdgcn_mfma_f32_16x16x32_bf16(a, b1, acc1, 0, 0, 0);
        acc2 = __builtin_amdgcn_mfma_f32_16x16x32_bf16(a, b2, acc2, 0, 0, 0);
        acc3 = __builtin_amdgcn_mfma_f32_16x16x32_bf16(a, b3, acc3, 0, 0, 0);
    }

    float ob = 1.0f - beta;
#pragma unroll
    for (int q = 0; q < 4; q++) {
        f32x4 accq = (q == 0) ? acc0 : (q == 1) ? acc1 : (q == 2) ? acc2 : acc3;
        int j0 = (jb + 2 * q) * 16;
#pragma unroll
        for (int r = 0; r < 4; r++) {
            int rowm = mt + lq * 4 + r;          // C/D: col=lane&15, row=quad*4+reg
            int dst = base + rowm;
            if (dst < N) {
                float sv = s_f32[rowm * HID + j0 + lrow];
                float h = fmaxf(ob * sv + beta * accq[r], 0.f);
                g_out[(size_t)dst * HID + j0 + lrow] = f2bf(s_dv[rowm] * h);
            }
        }
    }
}

// ---------- out = (g/dinv) @ W_out + b_out ----------
__global__ void out_k(const ushort_t* __restrict__ g, const float* __restrict__ dinv,
                      const float* __restrict__ Wout, const float* __restrict__ bout,
                      float* __restrict__ out, int N) {
    int t = threadIdx.x;
    int lane = t & 63;
    int wv = t >> 6;  // 4 waves/block, one node each
    int n = blockIdx.x * 4 + wv;
    if (n >= N) return;
    uint32 u = ((const uint32*)(g + (size_t)n * HID))[lane];
    float v = bf_lo(u) * Wout[lane * 2] + bf_hi(u) * Wout[lane * 2 + 1];
#pragma unroll
    for (int off = 32; off > 0; off >>= 1) v += __shfl_down(v, off, 64);
    if (lane == 0) out[n] = v / dinv[n] + bout[0];
}

extern "C" void kernel_launch(void* const* d_in, const int* in_sizes, int n_in,
                              void* d_out, int out_size, void* d_ws, size_t ws_size,
                              hipStream_t stream) {
    const float* x    = (const float*)d_in[0];
    const int*   ei   = (const int*)d_in[1];
    const float* Win  = (const float*)d_in[2];
    const float* bin  = (const float*)d_in[3];
    const float* convs= (const float*)d_in[4];
    const float* Wout = (const float*)d_in[5];
    const float* bout = (const float*)d_in[6];

    int N = in_sizes[0] / 256;
    int E = in_sizes[1] / 2;
    const int* row = ei;       // sources
    const int* col = ei + E;   // destinations

    char* ws = (char*)d_ws;
    size_t off = 0;
    auto alloc = [&](size_t bytes) -> char* {
        char* p = ws + off;
        off = (off + bytes + 255) & ~(size_t)255;
        return p;
    };
    int*      counts    = (int*)alloc((size_t)N * 4);
    int*      row_ptr   = (int*)alloc((size_t)(N + 1) * 4);
    int*      cursor    = (int*)alloc((size_t)N * 4);
    int*      blocksums = (int*)alloc(512 * 4);
    int*      blockoffs = (int*)alloc(512 * 4);
    float*    dinv      = (float*)alloc((size_t)N * 4);
    int*      srcS      = (int*)alloc((size_t)E * 4);
    short*    Wt        = (short*)alloc((size_t)8 * 128 * 128 * 2);
    short*    Winb      = (short*)alloc((size_t)256 * 128 * 2);
    ushort_t* h0b       = (ushort_t*)alloc((size_t)N * HID * 2);
    ushort_t* gA        = (ushort_t*)alloc((size_t)N * HID * 2);
    ushort_t* gB        = (ushort_t*)alloc((size_t)N * HID * 2);

    int eb = (E + 255) / 256;
    int nb = (N + 255) / 256;

    hipMemsetAsync(counts, 0, (size_t)N * 4, stream);
    degree_k<<<eb, 256, 0, stream>>>(col, counts, E);
    scan1_k<<<nb, 256, 0, stream>>>(counts, row_ptr, blocksums, dinv, N);
    scan2_k<<<1, 512, 0, stream>>>(blocksums, blockoffs, nb);
    scan3_k<<<nb, 256, 0, stream>>>(row_ptr, cursor, blockoffs, N, E);
    scatter_k<<<eb, 256, 0, stream>>>(row, col, cursor, srcS, E);
    wprep_k<<<512, 256, 0, stream>>>(convs, Wt);
    winprep_k<<<128, 256, 0, stream>>>(Win, Winb);

    int gb = (N + NB - 1) / NB;
    h0_k<<<gb, 256, 0, stream>>>(x, Winb, bin, dinv, h0b, gA, N);

    ushort_t* gin = gA;
    ushort_t* gout = gB;
    for (int i = 0; i < 8; i++) {
        float beta = (float)log(0.5 / (double)(i + 1) + 1.0);
        layer_k<<<gb, 256, 0, stream>>>(gin, gout, h0b, dinv, row_ptr, srcS,
                                        Wt + (size_t)i * 128 * 128, beta, N);
        ushort_t* tp = gin; gin = gout; gout = tp;
    }
    out_k<<<(N + 3) / 4, 256, 0, stream>>>(gin, dinv, Wout, bout, (float*)d_out, N);
}